// Round 11
// baseline (41.139 us; speedup 1.0000x reference)
//
#include <hip/hip_runtime.h>
#include <math.h>

#define NROWS 65536
#define DDIM 512
#define NUM_CLASSES 1000
#define NHB 16                     // histogram / scatter blocks
#define RPHB (NROWS / NHB)         // 4096 rows each
#define NSHARD 8

// ws layout (32-bit elements):
//   [0, 16000)          int   hist partials [NHB][NUM_CLASSES]
//   [16384, 81920)      int   sorted row indices [NROWS]
//   [81920, 90112)      float 8 sharded bin arrays [NSHARD][1024]
#define HIST_OFF 0
#define SORT_OFF 16384
#define BINS_OFF (16384 + NROWS)
#define WS_NEED ((size_t)(BINS_OFF + NSHARD * 1024) * 4)

__device__ inline float sqdiff4(float4 a, float4 b) {
    float dx = a.x - b.x, dy = a.y - b.y, dz = a.z - b.z, dw = a.w - b.w;
    return fmaf(dx, dx, fmaf(dy, dy, fmaf(dz, dz, dw * dw)));
}

// --- K1: per-block label histogram (LDS), plain-store partials (no init needed) ---
__global__ __launch_bounds__(1024) void CL_hist(
    const int* __restrict__ labels, int* __restrict__ wsI)
{
    __shared__ int cnt[NUM_CLASSES];
    const int t = threadIdx.x;
    if (t < NUM_CLASSES) cnt[t] = 0;
    __syncthreads();
    const int base = blockIdx.x * RPHB;
#pragma unroll
    for (int i = 0; i < RPHB / 1024; ++i)
        atomicAdd(&cnt[labels[base + i * 1024 + t]], 1);
    __syncthreads();
    if (t < NUM_CLASSES)
        wsI[HIST_OFF + blockIdx.x * NUM_CLASSES + t] = cnt[t];
}

// --- K2: redundant per-block scan of partials -> bases; scatter row indices.
//         Block 0 also zeroes the atomic bins (stores only, same-value safe). ---
__global__ __launch_bounds__(1024) void CL_scatter(
    const int* __restrict__ labels, int* __restrict__ wsI,
    float* __restrict__ wsF)
{
    __shared__ int scanbuf[1024];
    __shared__ int basech[NUM_CLASSES];
    __shared__ int lcnt[NUM_CLASSES];
    const int t = threadIdx.x;

    if (blockIdx.x == 0) {
#pragma unroll
        for (int i = 0; i < NSHARD; ++i)
            wsF[BINS_OFF + i * 1024 + t] = 0.0f;
    }

    // colsum(t) = total count of class t; myoff(t) = count in blocks before mine
    int colsum = 0, myoff = 0;
    if (t < NUM_CLASSES) {
        for (int b = 0; b < NHB; ++b) {
            const int v = wsI[HIST_OFF + b * NUM_CLASSES + t];
            colsum += v;
            if (b < (int)blockIdx.x) myoff += v;
        }
    }
    scanbuf[t] = (t < NUM_CLASSES) ? colsum : 0;
    __syncthreads();
    // inclusive Hillis-Steele scan over 1024 entries
    for (int off = 1; off < 1024; off <<= 1) {
        int v = scanbuf[t];
        if (t >= off) v += scanbuf[t - off];
        __syncthreads();
        scanbuf[t] = v;
        __syncthreads();
    }
    if (t < NUM_CLASSES) {
        const int excl = (t == 0) ? 0 : scanbuf[t - 1];
        basech[t] = excl + myoff;
        lcnt[t] = 0;
    }
    __syncthreads();

    const int base = blockIdx.x * RPHB;
#pragma unroll
    for (int i = 0; i < RPHB / 1024; ++i) {
        const int r = base + i * 1024 + t;
        const int l = labels[r];
        const int pos = basech[l] + atomicAdd(&lcnt[l], 1);
        wsI[SORT_OFF + pos] = r;
    }
}

// --- K3: accumulate in sorted order; center row held in registers per run ---
__global__ __launch_bounds__(256) void CL_accum_sorted(
    const float* __restrict__ x,
    const int* __restrict__ labels,
    const float* __restrict__ centers,
    const int* __restrict__ wsI,
    float* __restrict__ wsF)
{
    const int lane = threadIdx.x & 63;
    const int wid  = (blockIdx.x << 2) + (threadIdx.x >> 6);
    const int base = wid * 8;

    // prefetch this wave's 8 sorted rows + their labels (one gather each)
    int sr = 0, sl = 0;
    if (lane < 8) {
        sr = wsI[SORT_OFF + base + lane];
        sl = labels[sr];
    }

    float* __restrict__ bins =
        wsF + BINS_OFF + ((blockIdx.x & (NSHARD - 1)) << 10);

    float racc = 0.0f;
    int cur = -1;
    float4 c0, c1;
#pragma unroll
    for (int k = 0; k < 8; ++k) {
        const int r = __shfl(sr, k, 64);
        const int l = __shfl(sl, k, 64);
        if (l != cur) {                       // wave-uniform branch
            if (cur >= 0) {
                float red = racc;
#pragma unroll
                for (int off = 32; off > 0; off >>= 1)
                    red += __shfl_xor(red, off, 64);
                if (lane == 0) atomicAdd(&bins[cur], red);
            }
            cur = l;
            const float4* __restrict__ cr =
                reinterpret_cast<const float4*>(centers + (size_t)l * DDIM);
            c0 = cr[lane];
            c1 = cr[lane + 64];
            racc = 0.0f;
        }
        const float4* __restrict__ xr =
            reinterpret_cast<const float4*>(x + (size_t)r * DDIM);
        racc += sqdiff4(xr[lane], c0) + sqdiff4(xr[lane + 64], c1);
    }
    {
        float red = racc;
#pragma unroll
        for (int off = 32; off > 0; off >>= 1)
            red += __shfl_xor(red, off, 64);
        if (lane == 0) atomicAdd(&bins[cur], red);
    }
}

// --- K4: sum shards, sqrt, reduce, scale (bins pointer parameterized) ---
__global__ __launch_bounds__(256) void CL_final8(
    const float* __restrict__ bins, float* __restrict__ out)
{
    const int t = threadIdx.x, lane = t & 63;
    float s = 0.0f;
    if (t < NUM_CLASSES / 4) {
        float4 v = reinterpret_cast<const float4*>(bins)[t];
#pragma unroll
        for (int sh = 1; sh < NSHARD; ++sh) {
            float4 u = reinterpret_cast<const float4*>(bins + (sh << 10))[t];
            v.x += u.x; v.y += u.y; v.z += u.z; v.w += u.w;
        }
        s = sqrtf(v.x) + sqrtf(v.y) + sqrtf(v.z) + sqrtf(v.w);
    }
#pragma unroll
    for (int off = 32; off > 0; off >>= 1)
        s += __shfl_xor(s, off, 64);
    __shared__ float partial[4];
    if (lane == 0) partial[t >> 6] = s;
    __syncthreads();
    if (t == 0)
        out[0] = (partial[0] + partial[1] + partial[2] + partial[3])
                 / (float)NUM_CLASSES;
}

// ---------------- fallback (proven R8, 36.9 µs) if ws too small ----------------
__global__ __launch_bounds__(256) void CL_zero8(float* __restrict__ ws) {
    const int n = NSHARD * 1024;
    for (int i = threadIdx.x + blockIdx.x * 256; i < n; i += 256 * 8) ws[i] = 0.0f;
}
__global__ __launch_bounds__(256) void CL_accum8(
    const float* __restrict__ x, const int* __restrict__ labels,
    const float* __restrict__ centers, float* __restrict__ ws)
{
    const int wave = threadIdx.x >> 6, lane = threadIdx.x & 63;
    const int row = (blockIdx.x << 2) + wave;
    const int lbl = labels[row];
    const float4* xr = (const float4*)(x + (size_t)row * DDIM);
    const float4* cr = (const float4*)(centers + (size_t)lbl * DDIM);
    const float4 xv0 = xr[lane], xv1 = xr[lane + 64];
    const float4 cv0 = cr[lane], cv1 = cr[lane + 64];
    float acc = sqdiff4(xv0, cv0) + sqdiff4(xv1, cv1);
#pragma unroll
    for (int off = 32; off > 0; off >>= 1) acc += __shfl_xor(acc, off, 64);
    if (lane == 0)
        atomicAdd(&ws[((blockIdx.x & (NSHARD - 1)) << 10) + lbl], acc);
}

extern "C" void kernel_launch(void* const* d_in, const int* in_sizes, int n_in,
                              void* d_out, int out_size, void* d_ws, size_t ws_size,
                              hipStream_t stream) {
    const float* x       = (const float*)d_in[0];
    const int*   labels  = (const int*)d_in[1];
    const float* centers = (const float*)d_in[2];
    float* out = (float*)d_out;
    float* wsF = (float*)d_ws;
    int*   wsI = (int*)d_ws;

    if (ws_size >= WS_NEED) {
        CL_hist<<<NHB, 1024, 0, stream>>>(labels, wsI);
        CL_scatter<<<NHB, 1024, 0, stream>>>(labels, wsI, wsF);
        CL_accum_sorted<<<NROWS / 32, 256, 0, stream>>>(x, labels, centers, wsI, wsF);
        CL_final8<<<1, 256, 0, stream>>>(wsF + BINS_OFF, out);
    } else {
        CL_zero8<<<8, 256, 0, stream>>>(wsF);
        CL_accum8<<<NROWS / 4, 256, 0, stream>>>(x, labels, centers, wsF);
        CL_final8<<<1, 256, 0, stream>>>(wsF, out);
    }
}

// Round 13
// 36.740 us; speedup vs baseline: 1.1197x; 1.1197x over previous
//
#include <hip/hip_runtime.h>
#include <math.h>

#define NROWS 65536
#define DDIM 512
#define NUM_CLASSES 1000
#define NSHARD 8

// --- kernel 1: zero the 8 sharded bin arrays ---
__global__ __launch_bounds__(256) void CL_zero8(float* __restrict__ ws) {
    const int n = NSHARD * 1024;
    for (int i = threadIdx.x + blockIdx.x * 256; i < n; i += 256 * 8)
        ws[i] = 0.0f;
}

__device__ inline float sqdiff4(float4 a, float4 b) {
    float dx = a.x - b.x, dy = a.y - b.y, dz = a.z - b.z, dw = a.w - b.w;
    return fmaf(dx, dx, fmaf(dy, dy, fmaf(dz, dz, dw * dw)));
}

// --- kernel 2: 4 rows per wave, ALL 16 float4 loads forced in flight ---
// VGPR_Count was 20-28 in every profiled round: the compiler was scheduling
// loads just-before-use (~2 in flight), serializing the memory chain.
// sched_barrier(0) is a compile-time fence no instruction may cross: all 16
// loads (defined above it) must issue before any compute (below it) ->
// ~64 live VGPRs of load data, one coalesced waitcnt, true MLP-16.
__global__ __launch_bounds__(256) void CL_accum4(
    const float* __restrict__ x,
    const int* __restrict__ labels,
    const float* __restrict__ centers,
    float* __restrict__ ws)
{
    const int lane = threadIdx.x & 63;
    const int wid  = (blockIdx.x << 2) + (threadIdx.x >> 6);   // 0..16383
    const int r    = wid << 2;                                  // 4 rows

    // wave-uniform label loads (s_load) — issue first, longest chain
    const int l0 = labels[r + 0];
    const int l1 = labels[r + 1];
    const int l2 = labels[r + 2];
    const int l3 = labels[r + 3];

    // x rows are contiguous: row r+i begins at float4 offset i*128
    const float4* __restrict__ xr =
        reinterpret_cast<const float4*>(x + (size_t)r * DDIM);
    float4 xa0 = xr[lane +   0], xb0 = xr[lane +  64];
    float4 xa1 = xr[lane + 128], xb1 = xr[lane + 192];
    float4 xa2 = xr[lane + 256], xb2 = xr[lane + 320];
    float4 xa3 = xr[lane + 384], xb3 = xr[lane + 448];

    const float4* __restrict__ c0 =
        reinterpret_cast<const float4*>(centers + (size_t)l0 * DDIM);
    const float4* __restrict__ c1 =
        reinterpret_cast<const float4*>(centers + (size_t)l1 * DDIM);
    const float4* __restrict__ c2 =
        reinterpret_cast<const float4*>(centers + (size_t)l2 * DDIM);
    const float4* __restrict__ c3 =
        reinterpret_cast<const float4*>(centers + (size_t)l3 * DDIM);
    float4 ca0 = c0[lane], cb0 = c0[lane + 64];
    float4 ca1 = c1[lane], cb1 = c1[lane + 64];
    float4 ca2 = c2[lane], cb2 = c2[lane + 64];
    float4 ca3 = c3[lane], cb3 = c3[lane + 64];

    // compile-time scheduling fence: all loads above, all compute below
    __builtin_amdgcn_sched_barrier(0);

    float a0 = sqdiff4(xa0, ca0) + sqdiff4(xb0, cb0);
    float a1 = sqdiff4(xa1, ca1) + sqdiff4(xb1, cb1);
    float a2 = sqdiff4(xa2, ca2) + sqdiff4(xb2, cb2);
    float a3 = sqdiff4(xa3, ca3) + sqdiff4(xb3, cb3);

#pragma unroll
    for (int off = 32; off > 0; off >>= 1) {
        a0 += __shfl_xor(a0, off, 64);
        a1 += __shfl_xor(a1, off, 64);
        a2 += __shfl_xor(a2, off, 64);
        a3 += __shfl_xor(a3, off, 64);
    }

    // one atomic instruction, 4 active lanes, per-lane shard spread
    const float av = (lane == 0) ? a0 : (lane == 1) ? a1 : (lane == 2) ? a2 : a3;
    const int   ab = (lane == 0) ? l0 : (lane == 1) ? l1 : (lane == 2) ? l2 : l3;
    if (lane < 4)
        atomicAdd(&ws[(((wid + lane) & (NSHARD - 1)) << 10) + ab], av);
}

// --- kernel 3: sum 8 shards, sqrt, reduce, scale ---
__global__ __launch_bounds__(256) void CL_final8(
    const float* __restrict__ ws, float* __restrict__ out)
{
    const int t = threadIdx.x, lane = t & 63;
    float s = 0.0f;
    if (t < NUM_CLASSES / 4) {               // 250 threads, 1000 = 250 float4
        float4 v = reinterpret_cast<const float4*>(ws)[t];
#pragma unroll
        for (int sh = 1; sh < NSHARD; ++sh) {
            float4 u = reinterpret_cast<const float4*>(ws + (sh << 10))[t];
            v.x += u.x; v.y += u.y; v.z += u.z; v.w += u.w;
        }
        s = sqrtf(v.x) + sqrtf(v.y) + sqrtf(v.z) + sqrtf(v.w);
    }
#pragma unroll
    for (int off = 32; off > 0; off >>= 1)
        s += __shfl_xor(s, off, 64);

    __shared__ float partial[4];
    if (lane == 0) partial[t >> 6] = s;
    __syncthreads();
    if (t == 0)
        out[0] = (partial[0] + partial[1] + partial[2] + partial[3])
                 / (float)NUM_CLASSES;
}

extern "C" void kernel_launch(void* const* d_in, const int* in_sizes, int n_in,
                              void* d_out, int out_size, void* d_ws, size_t ws_size,
                              hipStream_t stream) {
    const float* x       = (const float*)d_in[0];
    const int*   labels  = (const int*)d_in[1];
    const float* centers = (const float*)d_in[2];
    float* out = (float*)d_out;
    float* ws  = (float*)d_ws;

    CL_zero8<<<8, 256, 0, stream>>>(ws);
    CL_accum4<<<NROWS / 16, 256, 0, stream>>>(x, labels, centers, ws);
    CL_final8<<<1, 256, 0, stream>>>(ws, out);
}